// Round 1
// baseline (422115.674 us; speedup 1.0000x reference)
//
#include <hip/hip_runtime.h>
#include <math.h>

// Problem constants
#define B 64
#define T 512
#define F 256
#define U 1024
#define NBLK 256
#define NTH 256

// ---------------- workspace layout (in floats) ----------------
// hT: [2 parity][3 layers][U][B]   transposed hidden state (u-major, b contiguous)
// cT: [3][U][B]                    cell state (single buffer, owner-block RMW)
// xbufT: [F][B]                    layer-0 input for current step (transposed)
// stats: [2 parity][2 (sum,sumsq)][B]
// cond: int[T]
// barrier: ints
static const size_t OFF_H = 0;
static const size_t SZ_H = (size_t)2 * 3 * U * B;        // 393216
static const size_t OFF_C = OFF_H + SZ_H;
static const size_t SZ_C = (size_t)3 * U * B;            // 196608
static const size_t OFF_X = OFF_C + SZ_C;
static const size_t SZ_X = (size_t)F * B;                // 16384
static const size_t OFF_STATS = OFF_X + SZ_X;            // 256 floats
static const size_t OFF_COND = OFF_STATS + 256;          // 512 ints (as floats slots)
static const size_t OFF_BAR = OFF_COND + 512;            // 1024 ints
static const size_t WS_FLOATS = OFF_BAR + 1024;          // 608000 floats = 2.43 MB

__device__ __forceinline__ float sigm(float x) {
    return 1.0f / (1.0f + __expf(-x));
}

// Hierarchical device-scope grid barrier.
// bar layout (ints): sub-counters at [i*64] for i in 0..7 (256B spacing),
// master at [512], generation flag at [576].
__device__ __forceinline__ void grid_barrier(int* bar, int epoch) {
    __syncthreads();
    if (threadIdx.x == 0) {
        __threadfence();  // release my block's data writes (agent scope)
        int* sub = bar + (blockIdx.x & 7) * 64;
        int* master = bar + 512;
        int* gen = bar + 576;
        int prev = atomicAdd(sub, 1);
        if (prev == 31) {                       // last block of my sub-group
            int pm = atomicAdd(master, 1);
            if (pm == 7) {                      // last block overall
                *master = 0;
                #pragma unroll
                for (int i = 0; i < 8; ++i) bar[i * 64] = 0;
                __threadfence();
                __hip_atomic_store(gen, epoch, __ATOMIC_RELEASE, __HIP_MEMORY_SCOPE_AGENT);
            }
        }
        while (__hip_atomic_load(gen, __ATOMIC_ACQUIRE, __HIP_MEMORY_SCOPE_AGENT) < epoch) {
            __builtin_amdgcn_s_sleep(1);
        }
    }
    __syncthreads();
}

// Prep: decode conditioned_lst (robust to bool-u8 vs int32 storage),
// initialize xbufT with input[:, 0, :] transposed.
__global__ void prep_kernel(const unsigned char* __restrict__ condraw,
                            const float* __restrict__ input,
                            float* __restrict__ ws) {
    __shared__ int s_not_int32;
    const int tid = threadIdx.x;
    if (tid == 0) s_not_int32 = 0;
    __syncthreads();
    // If stored as int32 (little-endian 0/1), bytes at idx%4!=0 are all zero
    // within the first 512 bytes. Reading 512 bytes is safe in either case.
    if (tid < 512 && (tid & 3) != 0) {
        if (condraw[tid] != 0) s_not_int32 = 1;
    }
    __syncthreads();
    const int is32 = (s_not_int32 == 0);
    int* condw = (int*)(ws + OFF_COND);
    if (tid < 512) {
        int cv = is32 ? ((const int*)condraw)[tid] : (int)condraw[tid];
        condw[tid] = (cv != 0) ? 1 : 0;
    }
    // xbufT[f][b] = input[b][0][f]
    for (int i = tid; i < F * B; i += blockDim.x) {
        const int f = i >> 6, b = i & 63;
        ws[OFF_X + i] = input[(size_t)b * (T * F) + f];
    }
}

__global__ void __launch_bounds__(NTH)
lstm_persistent(const float* __restrict__ input,
                const float* __restrict__ W0, const float* __restrict__ b0,
                const float* __restrict__ W1, const float* __restrict__ b1,
                const float* __restrict__ W2, const float* __restrict__ b2,
                const float* __restrict__ Wd, const float* __restrict__ bd,
                const float* __restrict__ gamma, const float* __restrict__ beta,
                float* __restrict__ out, float* __restrict__ ws) {
    const int g = blockIdx.x;
    const int tid = threadIdx.x;
    const int lane = tid & 63;                                     // lane = batch index
    const int wv = __builtin_amdgcn_readfirstlane(tid >> 6);       // wave id (uniform!)

    float* hT = ws + OFF_H;      // [2][3][U][B]
    float* cT = ws + OFF_C;      // [3][U][B]
    float* xbufT = ws + OFF_X;   // [F][B]
    float* stats = ws + OFF_STATS;
    const int* cond = (const int*)(ws + OFF_COND);
    int* bar = (int*)(ws + OFF_BAR);
    int epoch = 0;

    __shared__ float lds_part[4][16][64];  // 16 KB cross-wave reduction buffer

    const int u0 = g << 2;   // this block's u-quad (layers); 256 blocks * 4 = 1024
    const int f0 = g << 2;   // this block's f-quad (dense); only g < 64 active

    for (int t = 0; t < T; ++t) {
        const int p = t & 1;       // parity holding h_old
        const int pn = p ^ 1;      // parity receiving h_new

        // ---------------- LSTM layers ----------------
        for (int l = 0; l < 3; ++l) {
            const int K1 = (l == 0) ? F : U;   // size of x-part of concat
            const int K = K1 + U;
            const int kq = K >> 2;             // per-wave K slice (320 or 512)
            const int k0 = wv * kq;
            const int k1 = k0 + kq;
            const float* Wmat = (l == 0) ? W0 : ((l == 1) ? W1 : W2);
            const float* bvec = (l == 0) ? b0 : ((l == 1) ? b1 : b2);
            const float* xpart = (l == 0) ? xbufT
                                          : (hT + ((size_t)pn * 3 + (l - 1)) * U * B);
            const float* hpart = hT + ((size_t)p * 3 + l) * U * B;

            float acc[16];
            #pragma unroll
            for (int c = 0; c < 16; ++c) acc[c] = 0.0f;

            for (int k = k0; k < k1; ++k) {
                float xv;
                if (k < K1) xv = xpart[(size_t)k * B + lane];
                else        xv = hpart[(size_t)(k - K1) * B + lane];
                // weights: wave-uniform address -> s_load_dwordx4
                const float* wrow = Wmat + (size_t)k * (4 * U) + u0;
                #pragma unroll
                for (int q = 0; q < 4; ++q) {
                    const float4 w4 = *(const float4*)(wrow + (size_t)q * U);
                    acc[q * 4 + 0] = fmaf(w4.x, xv, acc[q * 4 + 0]);
                    acc[q * 4 + 1] = fmaf(w4.y, xv, acc[q * 4 + 1]);
                    acc[q * 4 + 2] = fmaf(w4.z, xv, acc[q * 4 + 2]);
                    acc[q * 4 + 3] = fmaf(w4.w, xv, acc[q * 4 + 3]);
                }
            }

            // cross-wave K reduction
            __syncthreads();
            #pragma unroll
            for (int c = 0; c < 16; ++c) lds_part[wv][c][lane] = acc[c];
            __syncthreads();

            // wave wv handles u offset jj = wv: gates i,g,f,o for (b=lane, u0+jj)
            {
                const int jj = wv;
                float zi = 0.f, zg = 0.f, zf = 0.f, zo = 0.f;
                #pragma unroll
                for (int w = 0; w < 4; ++w) {
                    zi += lds_part[w][0 * 4 + jj][lane];
                    zg += lds_part[w][1 * 4 + jj][lane];
                    zf += lds_part[w][2 * 4 + jj][lane];
                    zo += lds_part[w][3 * 4 + jj][lane];
                }
                zi += bvec[0 * U + u0 + jj];
                zg += bvec[1 * U + u0 + jj];
                zf += bvec[2 * U + u0 + jj];
                zo += bvec[3 * U + u0 + jj];
                const size_t cidx = ((size_t)l * U + (u0 + jj)) * B + lane;
                const float cold = cT[cidx];
                const float ig = sigm(zi);
                const float gg = tanhf(zg);
                const float fg = sigm(zf + 1.0f);   // forget_bias = 1.0
                const float og = sigm(zo);
                const float cnew = cold * fg + ig * gg;
                const float hnew = og * tanhf(cnew);
                cT[cidx] = cnew;
                hT[((size_t)pn * 3 + l) * U * B + (size_t)(u0 + jj) * B + lane] = hnew;
            }
            __syncthreads();
            grid_barrier(bar, ++epoch);
        }

        // ---------------- dense projection + LN stats ----------------
        float yv[4] = {0.f, 0.f, 0.f, 0.f};
        if (g < 64) {
            const float* h2 = hT + ((size_t)pn * 3 + 2) * U * B;
            float acc[4] = {0.f, 0.f, 0.f, 0.f};
            const int k0 = wv * (U / 4);
            const int k1 = k0 + (U / 4);
            for (int k = k0; k < k1; ++k) {
                const float xv = h2[(size_t)k * B + lane];
                const float4 w4 = *(const float4*)(Wd + (size_t)k * F + f0);
                acc[0] = fmaf(w4.x, xv, acc[0]);
                acc[1] = fmaf(w4.y, xv, acc[1]);
                acc[2] = fmaf(w4.z, xv, acc[2]);
                acc[3] = fmaf(w4.w, xv, acc[3]);
            }
            __syncthreads();
            #pragma unroll
            for (int jj = 0; jj < 4; ++jj) lds_part[wv][jj][lane] = acc[jj];
            __syncthreads();
            if (wv == 0) {
                const float4 bd4 = *(const float4*)(bd + f0);
                float s = 0.f, ss = 0.f;
                #pragma unroll
                for (int jj = 0; jj < 4; ++jj) {
                    float y = lds_part[0][jj][lane] + lds_part[1][jj][lane] +
                              lds_part[2][jj][lane] + lds_part[3][jj][lane];
                    y += (jj == 0) ? bd4.x : (jj == 1) ? bd4.y : (jj == 2) ? bd4.z : bd4.w;
                    yv[jj] = y;
                    s += y;
                    ss += y * y;
                }
                float* st = stats + (size_t)(t & 1) * 2 * B;
                atomicAdd(&st[lane], s);
                atomicAdd(&st[B + lane], ss);
            }
            __syncthreads();
        }
        grid_barrier(bar, ++epoch);

        // ---------------- LN + ReLU emit ----------------
        if (g < 64 && wv == 0) {
            const float* st = stats + (size_t)(t & 1) * 2 * B;
            const float mu = st[lane] * (1.0f / F);
            const float var = st[B + lane] * (1.0f / F) - mu * mu;
            const float rs = rsqrtf(var + 1e-12f);
            const float4 gm = *(const float4*)(gamma + f0);
            const float4 bt = *(const float4*)(beta + f0);
            float em[4];
            em[0] = fmaxf((yv[0] - mu) * rs * gm.x + bt.x, 0.0f);
            em[1] = fmaxf((yv[1] - mu) * rs * gm.y + bt.y, 0.0f);
            em[2] = fmaxf((yv[2] - mu) * rs * gm.z + bt.z, 0.0f);
            em[3] = fmaxf((yv[3] - mu) * rs * gm.w + bt.w, 0.0f);
            // output row t
            *(float4*)(out + (size_t)lane * (T * F) + (size_t)t * F + f0) =
                make_float4(em[0], em[1], em[2], em[3]);
            // next step's layer-0 input (teacher-forced or auto-conditioned)
            if (t + 1 < T) {
                float xn[4];
                if (cond[t + 1] != 0) {
                    const float4 iv = *(const float4*)(input + (size_t)lane * (T * F) +
                                                       (size_t)(t + 1) * F + f0);
                    xn[0] = iv.x; xn[1] = iv.y; xn[2] = iv.z; xn[3] = iv.w;
                } else {
                    xn[0] = em[0]; xn[1] = em[1]; xn[2] = em[2]; xn[3] = em[3];
                }
                #pragma unroll
                for (int jj = 0; jj < 4; ++jj)
                    xbufT[(size_t)(f0 + jj) * B + lane] = xn[jj];
            }
        }
        // zero the other-parity stats for step t+1 (its readers finished at t-1)
        if (g == 0 && wv == 1) {
            float* st2 = stats + (size_t)((t + 1) & 1) * 2 * B;
            st2[lane] = 0.0f;
            st2[B + lane] = 0.0f;
        }
        grid_barrier(bar, ++epoch);
    }
}

extern "C" void kernel_launch(void* const* d_in, const int* in_sizes, int n_in,
                              void* d_out, int out_size, void* d_ws, size_t ws_size,
                              hipStream_t stream) {
    const float* input = (const float*)d_in[0];
    const unsigned char* condraw = (const unsigned char*)d_in[1];
    const float* W0 = (const float*)d_in[2];
    const float* b0 = (const float*)d_in[3];
    const float* W1 = (const float*)d_in[4];
    const float* b1 = (const float*)d_in[5];
    const float* W2 = (const float*)d_in[6];
    const float* b2 = (const float*)d_in[7];
    const float* Wd = (const float*)d_in[8];
    const float* bd = (const float*)d_in[9];
    const float* gamma = (const float*)d_in[10];
    const float* beta = (const float*)d_in[11];
    float* out = (float*)d_out;
    float* ws = (float*)d_ws;

    size_t need = WS_FLOATS * sizeof(float);
    if (need > ws_size) need = ws_size;  // (should never trigger; 2.43 MB)
    hipMemsetAsync(d_ws, 0, need, stream);
    prep_kernel<<<1, 512, 0, stream>>>(condraw, input, ws);
    lstm_persistent<<<NBLK, NTH, 0, stream>>>(input, W0, b0, W1, b1, W2, b2,
                                              Wd, bd, gamma, beta, out, ws);
}

// Round 2
// 172610.999 us; speedup vs baseline: 2.4455x; 2.4455x over previous
//
#include <hip/hip_runtime.h>
#include <math.h>

// Problem constants
#define B 64
#define T 512
#define F 256
#define U 1024
#define NBLK 256
#define NTH 512

// ---------------- workspace layout (in floats) ----------------
static const size_t OFF_H = 0;
static const size_t SZ_H = (size_t)2 * 3 * U * B;        // 393216
static const size_t OFF_C = OFF_H + SZ_H;
static const size_t SZ_C = (size_t)3 * U * B;            // 196608
static const size_t OFF_X = OFF_C + SZ_C;
static const size_t SZ_X = (size_t)F * B;                // 16384
static const size_t OFF_STATS = OFF_X + SZ_X;            // 256 floats
static const size_t OFF_COND = OFF_STATS + 256;          // 512 ints
static const size_t OFF_BAR = OFF_COND + 512;            // 1024 ints
static const size_t OFF_PW0 = OFF_BAR + 1024;            // 608000 (16-aligned)
static const size_t SZ_PW0 = (size_t)1280 * 4096;        // 5242880
static const size_t OFF_PW1 = OFF_PW0 + SZ_PW0;
static const size_t SZ_PW12 = (size_t)2048 * 4096;       // 8388608
static const size_t OFF_PW2 = OFF_PW1 + SZ_PW12;
static const size_t WS_STATE_FLOATS = OFF_BAR + 1024;    // 608000 (zeroed region)
static const size_t WS_PACKED_FLOATS = OFF_PW2 + SZ_PW12;

__device__ __forceinline__ float sigm(float x) {
    return 1.0f / (1.0f + __expf(-x));
}

// column-quad swizzle: blocks sharing a 64B weight line sit on the same XCD
__device__ __host__ __forceinline__ int quad_of_block(int g) {
    return ((g & 7) << 5) | (g >> 3);   // (g%8)*32 + g/8, bijective on [0,256)
}

// Hierarchical device-scope grid barrier.
__device__ __forceinline__ void grid_barrier(int* bar, int epoch) {
    __syncthreads();
    if (threadIdx.x == 0) {
        __threadfence();
        int* sub = bar + (blockIdx.x & 7) * 64;
        int* master = bar + 512;
        int* gen = bar + 576;
        int prev = atomicAdd(sub, 1);
        if (prev == 31) {
            int pm = atomicAdd(master, 1);
            if (pm == 7) {
                *master = 0;
                #pragma unroll
                for (int i = 0; i < 8; ++i) bar[i * 64] = 0;
                __threadfence();
                __hip_atomic_store(gen, epoch, __ATOMIC_RELEASE, __HIP_MEMORY_SCOPE_AGENT);
            }
        }
        while (__hip_atomic_load(gen, __ATOMIC_ACQUIRE, __HIP_MEMORY_SCOPE_AGENT) < epoch) {
            __builtin_amdgcn_s_sleep(1);
        }
    }
    __syncthreads();
}

__global__ void prep_kernel(const unsigned char* __restrict__ condraw,
                            const float* __restrict__ input,
                            float* __restrict__ ws) {
    __shared__ int s_not_int32;
    const int tid = threadIdx.x;
    if (tid == 0) s_not_int32 = 0;
    __syncthreads();
    if (tid < 512 && (tid & 3) != 0) {
        if (condraw[tid] != 0) s_not_int32 = 1;
    }
    __syncthreads();
    const int is32 = (s_not_int32 == 0);
    int* condw = (int*)(ws + OFF_COND);
    if (tid < 512) {
        int cv = is32 ? ((const int*)condraw)[tid] : (int)condraw[tid];
        condw[tid] = (cv != 0) ? 1 : 0;
    }
    for (int i = tid; i < F * B; i += blockDim.x) {
        const int f = i >> 6, b = i & 63;
        ws[OFF_X + i] = input[(size_t)b * (T * F) + f];
    }
}

// Repack weights into per-block contiguous streams:
// PWl[g][k][c], c=0..15 <-> gate q=c>>2, unit u0+ (c&3), u0 = 4*quad_of_block(g)
__global__ void repack_kernel(const float* __restrict__ W0,
                              const float* __restrict__ W1,
                              const float* __restrict__ W2,
                              float* __restrict__ ws) {
    const size_t stride = (size_t)gridDim.x * blockDim.x;
    const size_t tid = (size_t)blockIdx.x * blockDim.x + threadIdx.x;
    // layer 0 (K=1280)
    for (size_t i = tid; i < SZ_PW0; i += stride) {
        const int g = (int)(i / (1280 * 16));
        const int r = (int)(i % (1280 * 16));
        const int k = r >> 4, c = r & 15;
        const int qi = quad_of_block(g);
        ws[OFF_PW0 + i] = W0[(size_t)k * 4096 + ((c >> 2) << 10) + (qi << 2) + (c & 3)];
    }
    // layers 1,2 (K=2048)
    for (size_t i = tid; i < SZ_PW12; i += stride) {
        const int g = (int)(i / (2048 * 16));
        const int r = (int)(i % (2048 * 16));
        const int k = r >> 4, c = r & 15;
        const int qi = quad_of_block(g);
        const size_t src = (size_t)k * 4096 + ((c >> 2) << 10) + (qi << 2) + (c & 3);
        ws[OFF_PW1 + i] = W1[src];
        ws[OFF_PW2 + i] = W2[src];
    }
}

__global__ void __launch_bounds__(NTH)
lstm_persistent(const float* __restrict__ input,
                const float* __restrict__ W0, const float* __restrict__ b0,
                const float* __restrict__ W1, const float* __restrict__ b1,
                const float* __restrict__ W2, const float* __restrict__ b2,
                const float* __restrict__ Wd, const float* __restrict__ bd,
                const float* __restrict__ gamma, const float* __restrict__ beta,
                float* __restrict__ out, float* __restrict__ ws, int packed) {
    const int g = blockIdx.x;
    const int tid = threadIdx.x;
    const int lane = tid & 63;                                // lane = batch index
    const int wv = __builtin_amdgcn_readfirstlane(tid >> 6);  // wave id 0..7 (uniform)

    float* hT = ws + OFF_H;
    float* cT = ws + OFF_C;
    float* xbufT = ws + OFF_X;
    float* stats = ws + OFF_STATS;
    const int* cond = (const int*)(ws + OFF_COND);
    int* bar = (int*)(ws + OFF_BAR);
    int epoch = 0;

    __shared__ float lds_part[8][16][64];  // 32 KB cross-wave reduction buffer

    const int qi = quad_of_block(g);
    const int u0 = qi << 2;   // this block's unit-quad (swizzled)
    const int f0 = g << 2;    // dense: block g<64 owns f0..f0+3

    for (int t = 0; t < T; ++t) {
        const int p = t & 1;
        const int pn = p ^ 1;

        // ---------------- LSTM layers ----------------
        for (int l = 0; l < 3; ++l) {
            const int K1 = (l == 0) ? F : U;
            const int K = K1 + U;
            const int kq = K >> 3;          // per-wave K slice (160 or 256)
            const int k0 = wv * kq;
            const int k1 = k0 + kq;
            const float* bvec = (l == 0) ? b0 : ((l == 1) ? b1 : b2);
            const float* xpart = (l == 0) ? xbufT
                                          : (hT + ((size_t)pn * 3 + (l - 1)) * U * B);
            const float* hpart = hT + ((size_t)p * 3 + l) * U * B;

            float acc[16];
            #pragma unroll
            for (int c = 0; c < 16; ++c) acc[c] = 0.0f;

            if (packed) {
                const float* PWl = (l == 0) ? (ws + OFF_PW0)
                                            : ((l == 1) ? (ws + OFF_PW1) : (ws + OFF_PW2));
                const float* pw = PWl + ((size_t)g * K + k0) * 16;
                #pragma unroll 4
                for (int k = k0; k < k1; ++k, pw += 16) {
                    const float* src = (k < K1) ? (xpart + (size_t)k * B)
                                                : (hpart + (size_t)(k - K1) * B);
                    const float xv = src[lane];
                    const float4 w0 = ((const float4*)pw)[0];
                    const float4 w1 = ((const float4*)pw)[1];
                    const float4 w2 = ((const float4*)pw)[2];
                    const float4 w3 = ((const float4*)pw)[3];
                    acc[0]  = fmaf(w0.x, xv, acc[0]);
                    acc[1]  = fmaf(w0.y, xv, acc[1]);
                    acc[2]  = fmaf(w0.z, xv, acc[2]);
                    acc[3]  = fmaf(w0.w, xv, acc[3]);
                    acc[4]  = fmaf(w1.x, xv, acc[4]);
                    acc[5]  = fmaf(w1.y, xv, acc[5]);
                    acc[6]  = fmaf(w1.z, xv, acc[6]);
                    acc[7]  = fmaf(w1.w, xv, acc[7]);
                    acc[8]  = fmaf(w2.x, xv, acc[8]);
                    acc[9]  = fmaf(w2.y, xv, acc[9]);
                    acc[10] = fmaf(w2.z, xv, acc[10]);
                    acc[11] = fmaf(w2.w, xv, acc[11]);
                    acc[12] = fmaf(w3.x, xv, acc[12]);
                    acc[13] = fmaf(w3.y, xv, acc[13]);
                    acc[14] = fmaf(w3.z, xv, acc[14]);
                    acc[15] = fmaf(w3.w, xv, acc[15]);
                }
            } else {
                const float* Wmat = (l == 0) ? W0 : ((l == 1) ? W1 : W2);
                #pragma unroll 2
                for (int k = k0; k < k1; ++k) {
                    const float* src = (k < K1) ? (xpart + (size_t)k * B)
                                                : (hpart + (size_t)(k - K1) * B);
                    const float xv = src[lane];
                    const float* wrow = Wmat + (size_t)k * (4 * U) + u0;
                    #pragma unroll
                    for (int q = 0; q < 4; ++q) {
                        const float4 w4 = *(const float4*)(wrow + (size_t)q * U);
                        acc[q * 4 + 0] = fmaf(w4.x, xv, acc[q * 4 + 0]);
                        acc[q * 4 + 1] = fmaf(w4.y, xv, acc[q * 4 + 1]);
                        acc[q * 4 + 2] = fmaf(w4.z, xv, acc[q * 4 + 2]);
                        acc[q * 4 + 3] = fmaf(w4.w, xv, acc[q * 4 + 3]);
                    }
                }
            }

            // cross-wave K reduction (8 partials)
            __syncthreads();
            #pragma unroll
            for (int c = 0; c < 16; ++c) lds_part[wv][c][lane] = acc[c];
            __syncthreads();

            if (wv < 4) {
                const int jj = wv;   // unit offset within quad
                float zi = 0.f, zg = 0.f, zf = 0.f, zo = 0.f;
                #pragma unroll
                for (int w = 0; w < 8; ++w) {
                    zi += lds_part[w][0 * 4 + jj][lane];
                    zg += lds_part[w][1 * 4 + jj][lane];
                    zf += lds_part[w][2 * 4 + jj][lane];
                    zo += lds_part[w][3 * 4 + jj][lane];
                }
                zi += bvec[0 * U + u0 + jj];
                zg += bvec[1 * U + u0 + jj];
                zf += bvec[2 * U + u0 + jj];
                zo += bvec[3 * U + u0 + jj];
                const size_t cidx = ((size_t)l * U + (u0 + jj)) * B + lane;
                const float cold = cT[cidx];
                const float ig = sigm(zi);
                const float gg = tanhf(zg);
                const float fg = sigm(zf + 1.0f);
                const float og = sigm(zo);
                const float cnew = cold * fg + ig * gg;
                const float hnew = og * tanhf(cnew);
                cT[cidx] = cnew;
                hT[((size_t)pn * 3 + l) * U * B + (size_t)(u0 + jj) * B + lane] = hnew;
            }
            __syncthreads();
            grid_barrier(bar, ++epoch);
        }

        // ---------------- dense projection + LN stats ----------------
        float yv[4] = {0.f, 0.f, 0.f, 0.f};
        if (g < 64) {
            const float* h2 = hT + ((size_t)pn * 3 + 2) * U * B;
            float acc[4] = {0.f, 0.f, 0.f, 0.f};
            const int kq = U >> 3;           // 128
            const int k0 = wv * kq;
            const int k1 = k0 + kq;
            #pragma unroll 4
            for (int k = k0; k < k1; ++k) {
                const float xv = h2[(size_t)k * B + lane];
                const float4 w4 = *(const float4*)(Wd + (size_t)k * F + f0);
                acc[0] = fmaf(w4.x, xv, acc[0]);
                acc[1] = fmaf(w4.y, xv, acc[1]);
                acc[2] = fmaf(w4.z, xv, acc[2]);
                acc[3] = fmaf(w4.w, xv, acc[3]);
            }
            __syncthreads();
            #pragma unroll
            for (int jj = 0; jj < 4; ++jj) lds_part[wv][jj][lane] = acc[jj];
            __syncthreads();
            if (wv == 0) {
                const float4 bd4 = *(const float4*)(bd + f0);
                float s = 0.f, ss = 0.f;
                #pragma unroll
                for (int jj = 0; jj < 4; ++jj) {
                    float y = 0.f;
                    #pragma unroll
                    for (int w = 0; w < 8; ++w) y += lds_part[w][jj][lane];
                    y += (jj == 0) ? bd4.x : (jj == 1) ? bd4.y : (jj == 2) ? bd4.z : bd4.w;
                    yv[jj] = y;
                    s += y;
                    ss += y * y;
                }
                float* st = stats + (size_t)(t & 1) * 2 * B;
                atomicAdd(&st[lane], s);
                atomicAdd(&st[B + lane], ss);
            }
            __syncthreads();
        }
        grid_barrier(bar, ++epoch);

        // ---------------- LN + ReLU emit ----------------
        if (g < 64 && wv == 0) {
            const float* st = stats + (size_t)(t & 1) * 2 * B;
            const float mu = st[lane] * (1.0f / F);
            const float var = st[B + lane] * (1.0f / F) - mu * mu;
            const float rs = rsqrtf(var + 1e-12f);
            const float4 gm = *(const float4*)(gamma + f0);
            const float4 bt = *(const float4*)(beta + f0);
            float em[4];
            em[0] = fmaxf((yv[0] - mu) * rs * gm.x + bt.x, 0.0f);
            em[1] = fmaxf((yv[1] - mu) * rs * gm.y + bt.y, 0.0f);
            em[2] = fmaxf((yv[2] - mu) * rs * gm.z + bt.z, 0.0f);
            em[3] = fmaxf((yv[3] - mu) * rs * gm.w + bt.w, 0.0f);
            *(float4*)(out + (size_t)lane * (T * F) + (size_t)t * F + f0) =
                make_float4(em[0], em[1], em[2], em[3]);
            if (t + 1 < T) {
                float xn[4];
                if (cond[t + 1] != 0) {
                    const float4 iv = *(const float4*)(input + (size_t)lane * (T * F) +
                                                       (size_t)(t + 1) * F + f0);
                    xn[0] = iv.x; xn[1] = iv.y; xn[2] = iv.z; xn[3] = iv.w;
                } else {
                    xn[0] = em[0]; xn[1] = em[1]; xn[2] = em[2]; xn[3] = em[3];
                }
                #pragma unroll
                for (int jj = 0; jj < 4; ++jj)
                    xbufT[(size_t)(f0 + jj) * B + lane] = xn[jj];
            }
        }
        if (g == 0 && wv == 1) {
            float* st2 = stats + (size_t)((t + 1) & 1) * 2 * B;
            st2[lane] = 0.0f;
            st2[B + lane] = 0.0f;
        }
        grid_barrier(bar, ++epoch);
    }
}

extern "C" void kernel_launch(void* const* d_in, const int* in_sizes, int n_in,
                              void* d_out, int out_size, void* d_ws, size_t ws_size,
                              hipStream_t stream) {
    const float* input = (const float*)d_in[0];
    const unsigned char* condraw = (const unsigned char*)d_in[1];
    const float* W0 = (const float*)d_in[2];
    const float* b0 = (const float*)d_in[3];
    const float* W1 = (const float*)d_in[4];
    const float* b1 = (const float*)d_in[5];
    const float* W2 = (const float*)d_in[6];
    const float* b2 = (const float*)d_in[7];
    const float* Wd = (const float*)d_in[8];
    const float* bd = (const float*)d_in[9];
    const float* gamma = (const float*)d_in[10];
    const float* beta = (const float*)d_in[11];
    float* out = (float*)d_out;
    float* ws = (float*)d_ws;

    const int packed = (ws_size >= WS_PACKED_FLOATS * sizeof(float)) ? 1 : 0;

    size_t zero_bytes = WS_STATE_FLOATS * sizeof(float);
    if (zero_bytes > ws_size) zero_bytes = ws_size;
    hipMemsetAsync(d_ws, 0, zero_bytes, stream);
    prep_kernel<<<1, 512, 0, stream>>>(condraw, input, ws);
    if (packed) repack_kernel<<<2048, 256, 0, stream>>>(W0, W1, W2, ws);
    lstm_persistent<<<NBLK, NTH, 0, stream>>>(input, W0, b0, W1, b1, W2, b2,
                                              Wd, bd, gamma, beta, out, ws, packed);
}

// Round 4
// 110326.465 us; speedup vs baseline: 3.8261x; 1.5645x over previous
//
#include <hip/hip_runtime.h>
#include <math.h>

// Problem constants
#define B 64
#define T 512
#define F 256
#define U 1024
#define NBLK 256
#define NTH 256
#define WPAD 68   // zbuf row stride (floats): 68%32=4 -> conflict-free b128 partial stores

typedef unsigned short ushort_t;
typedef __attribute__((ext_vector_type(8))) _Float16 f16x8_t;  // MFMA A/B frag (4 VGPR)
typedef __attribute__((ext_vector_type(4))) float f32x4_t;     // MFMA C/D frag

// ---------------- workspace layout (BYTE offsets) ----------------
static const size_t OFF_HT2  = 0;                  // fp32 h2 [U][B] for dense: 262144
static const size_t OFF_STATS= 262144;             // fp32 [2 parity][2][B]: 1024
static const size_t OFF_COND = 263424;             // int[512]: 2048
static const size_t OFF_BAR  = 265472;             // int[1024]: 4096
static const size_t OFF_HB   = 269568;             // f16 h [2 parity][3 layer][B][U]: 786432
static const size_t OFF_XB   = 1056000;            // f16 xbuf [B][F]: 32768
static const size_t OFF_PW0  = 1088768;            // f16 [256 g][40 kt][64 lane][8]: 10485760
static const size_t OFF_PW1  = 11574528;           // f16 [256][64][64][8]: 16777216
static const size_t OFF_PW2  = 28351744;           // f16 [256][64][64][8]: 16777216
static const size_t WS_BYTES = 45128960;
static const size_t ZERO_BYTES = OFF_PW0;          // state region to zero each launch

__device__ __forceinline__ float sigm(float x) {
    return 1.0f / (1.0f + __expf(-x));
}

__device__ __forceinline__ ushort_t f2h(float x) {   // RNE fp32->fp16
    _Float16 h = (_Float16)x;
    union { _Float16 h; ushort_t u; } v; v.h = h;
    return v.u;
}

// Hierarchical device-scope grid barrier (proven rounds 1-2).
__device__ __forceinline__ void grid_barrier(int* bar, int epoch) {
    __syncthreads();
    if (threadIdx.x == 0) {
        __threadfence();
        int* sub = bar + (blockIdx.x & 7) * 64;
        int* master = bar + 512;
        int* gen = bar + 576;
        int prev = atomicAdd(sub, 1);
        if (prev == 31) {
            int pm = atomicAdd(master, 1);
            if (pm == 7) {
                *master = 0;
                #pragma unroll
                for (int i = 0; i < 8; ++i) bar[i * 64] = 0;
                __threadfence();
                __hip_atomic_store(gen, epoch, __ATOMIC_RELEASE, __HIP_MEMORY_SCOPE_AGENT);
            }
        }
        while (__hip_atomic_load(gen, __ATOMIC_ACQUIRE, __HIP_MEMORY_SCOPE_AGENT) < epoch) {
            __builtin_amdgcn_s_sleep(1);
        }
    }
    __syncthreads();
}

// Prep: decode conditioned_lst (bool-u8 vs int32 sniff), init f16 xbuf from input[:,0,:].
__global__ void prep_kernel(const unsigned char* __restrict__ condraw,
                            const float* __restrict__ input,
                            unsigned char* __restrict__ wsb) {
    __shared__ int s_not_int32;
    const int tid = threadIdx.x;
    if (tid == 0) s_not_int32 = 0;
    __syncthreads();
    if (tid < 512 && (tid & 3) != 0) {
        if (condraw[tid] != 0) s_not_int32 = 1;
    }
    __syncthreads();
    const int is32 = (s_not_int32 == 0);
    int* condw = (int*)(wsb + OFF_COND);
    if (tid < 512) {
        int cv = is32 ? ((const int*)condraw)[tid] : (int)condraw[tid];
        condw[tid] = (cv != 0) ? 1 : 0;
    }
    ushort_t* xb = (ushort_t*)(wsb + OFF_XB);
    for (int i = tid; i < B * F; i += blockDim.x) {
        const int b = i >> 8, f = i & 255;
        xb[i] = f2h(input[(size_t)b * (T * F) + f]);
    }
}

// Repack fp32 weights -> fp16 in MFMA B-fragment order:
// PW_l[((g*KT + kt)*64 + L)*8 + j] = W_l[k][col], k = kt*32 + (L>>4)*8 + j,
// n = L&15, col = (n>>2)*1024 + g*4 + (n&3)   (gate q = n>>2, unit u0+(n&3))
__global__ void repack_kernel(const float* __restrict__ W0,
                              const float* __restrict__ W1,
                              const float* __restrict__ W2,
                              unsigned char* __restrict__ wsb) {
    ushort_t* P0 = (ushort_t*)(wsb + OFF_PW0);
    ushort_t* P1 = (ushort_t*)(wsb + OFF_PW1);
    ushort_t* P2 = (ushort_t*)(wsb + OFF_PW2);
    const size_t stride = (size_t)gridDim.x * blockDim.x;
    const size_t tid = (size_t)blockIdx.x * blockDim.x + threadIdx.x;
    const size_t N0 = (size_t)256 * 40 * 512;
    const size_t N12 = (size_t)256 * 64 * 512;
    for (size_t i = tid; i < N0; i += stride) {
        const int g = (int)(i / 20480);
        const int r = (int)(i % 20480);
        const int kt = r >> 9, s = r & 511, L = s >> 3, j = s & 7;
        const int k = kt * 32 + ((L >> 4) << 3) + j;
        const int n = L & 15;
        const int col = ((n >> 2) << 10) + (g << 2) + (n & 3);
        P0[i] = f2h(W0[(size_t)k * 4096 + col]);
    }
    for (size_t i = tid; i < N12; i += stride) {
        const int g = (int)(i / 32768);
        const int r = (int)(i % 32768);
        const int kt = r >> 9, s = r & 511, L = s >> 3, j = s & 7;
        const int k = kt * 32 + ((L >> 4) << 3) + j;
        const int n = L & 15;
        const int col = ((n >> 2) << 10) + (g << 2) + (n & 3);
        const size_t src = (size_t)k * 4096 + col;
        P1[i] = f2h(W1[src]);
        P2[i] = f2h(W2[src]);
    }
}

__global__ void __launch_bounds__(NTH)
lstm_persistent(const float* __restrict__ input,
                const float* __restrict__ b0, const float* __restrict__ b1,
                const float* __restrict__ b2,
                const float* __restrict__ Wd, const float* __restrict__ bd,
                const float* __restrict__ gamma, const float* __restrict__ beta,
                float* __restrict__ out, unsigned char* __restrict__ wsb) {
    const int g = blockIdx.x;
    const int tid = threadIdx.x;
    const int lane = tid & 63;
    const int wv = __builtin_amdgcn_readfirstlane(tid >> 6);  // 0..3
    const int ln15 = lane & 15;
    const int quad = lane >> 4;
    const int kofs = quad << 3;          // A/B frag k offset: quad*8

    float* hT2 = (float*)(wsb + OFF_HT2);          // fp32 [U][B]
    float* stats = (float*)(wsb + OFF_STATS);
    const int* cond = (const int*)(wsb + OFF_COND);
    int* bar = (int*)(wsb + OFF_BAR);
    ushort_t* hb = (ushort_t*)(wsb + OFF_HB);      // f16 [2][3][B][U]
    ushort_t* xb = (ushort_t*)(wsb + OFF_XB);      // f16 [B][F]
    const ushort_t* PWa[3] = {(const ushort_t*)(wsb + OFF_PW0),
                              (const ushort_t*)(wsb + OFF_PW1),
                              (const ushort_t*)(wsb + OFF_PW2)};

    __shared__ float zbuf[64 * WPAD];   // [wv*16+n][m] padded; 17.4 KB

    const int u0 = g << 2;   // block's unit quad
    const int f0 = g << 2;   // dense cols (g < 64)

    // epilogue thread mapping: one thread per (batch, unit-in-quad)
    const int eb = tid & 63;
    const int eu = tid >> 6;
    float creg[3] = {0.f, 0.f, 0.f};   // fp32 cell state, register-resident

    int epoch = 0;
    for (int t = 0; t < T; ++t) {
        const int p = t & 1;
        const int pn = p ^ 1;

        // ---------------- LSTM layers: MFMA z^(l) = X W ----------------
        #pragma unroll
        for (int l = 0; l < 3; ++l) {
            const int K1 = (l == 0) ? F : U;       // x-part length (ktile-aligned)
            const int KT = (l == 0) ? 40 : 64;     // total ktiles
            const int KTW = KT >> 2;               // ktiles per wave: 10 / 16
            const int S1 = (l == 0) ? F : U;       // x-part row stride
            const ushort_t* xsrc = (l == 0) ? xb
                                 : (hb + ((size_t)(pn * 3 + (l - 1))) * B * U);
            const ushort_t* hsrc = hb + ((size_t)(p * 3 + l)) * B * U;
            const ushort_t* pwb = PWa[l] + (size_t)g * KT * 512;

            f32x4_t acc[4];
            #pragma unroll
            for (int mt = 0; mt < 4; ++mt) acc[mt] = (f32x4_t){0.f, 0.f, 0.f, 0.f};

            const int kt0 = wv * KTW;
            f16x8_t Ab[4][4];
            f16x8_t Bb[4];

            auto LOADKT = [&](int slot, int i) {
                const int kt = kt0 + i;
                Bb[slot] = *(const f16x8_t*)(pwb + (size_t)kt * 512 + lane * 8);
                const int kg = kt * 32;
                const ushort_t* ab;
                int rs;
                if (kg < K1) { ab = xsrc + kg; rs = S1; }
                else         { ab = hsrc + (kg - K1); rs = U; }
                const ushort_t* lp = ab + (size_t)ln15 * rs + kofs;
                #pragma unroll
                for (int mt = 0; mt < 4; ++mt)
                    Ab[slot][mt] = *(const f16x8_t*)(lp + (size_t)mt * 16 * rs);
            };

            // depth-3 software pipeline over this wave's ktiles
            LOADKT(0, 0); LOADKT(1, 1); LOADKT(2, 2);
            #pragma unroll
            for (int i = 0; i < KTW; ++i) {
                const int pre = i + 3;
                if (pre < KTW) LOADKT(pre & 3, pre);
                const int cur = i & 3;
                #pragma unroll
                for (int mt = 0; mt < 4; ++mt)
                    acc[mt] = __builtin_amdgcn_mfma_f32_16x16x32_f16(
                        Ab[cur][mt], Bb[cur], acc[mt], 0, 0, 0);
            }

            // cross-wave K reduction via LDS: row = wv*16 + n, col m = mt*16+quad*4+reg
            __syncthreads();
            {
                float* zrow = zbuf + (size_t)(wv * 16 + ln15) * WPAD;
                #pragma unroll
                for (int mt = 0; mt < 4; ++mt)
                    *(f32x4_t*)(zrow + mt * 16 + (quad << 2)) = acc[mt];
            }
            __syncthreads();

            // gate epilogue: thread -> (b=eb, unit u0+eu); cols n = q*4+eu
            {
                const float* bvec = (l == 0) ? b0 : ((l == 1) ? b1 : b2);
                float z[4];
                #pragma unroll
                for (int q = 0; q < 4; ++q) {
                    float s = bvec[(q << 10) + u0 + eu];
                    #pragma unroll
                    for (int w = 0; w < 4; ++w)
                        s += zbuf[(size_t)(w * 16 + q * 4 + eu) * WPAD + eb];
                    z[q] = s;
                }
                const float ig = sigm(z[0]);
                const float gg = tanhf(z[1]);
                const float fg = sigm(z[2] + 1.0f);   // forget_bias = 1.0
                const float og = sigm(z[3]);
                const float cn = creg[l] * fg + ig * gg;
                const float hn = og * tanhf(cn);
                creg[l] = cn;
                hb[((size_t)(pn * 3 + l)) * B * U + (size_t)eb * U + u0 + eu] = f2h(hn);
                if (l == 2) hT2[(size_t)(u0 + eu) * B + eb] = hn;   // fp32 for dense
            }
            grid_barrier(bar, ++epoch);
        }

        // ---------------- dense projection + LN stats (fp32 VALU) ----------------
        float yv[4] = {0.f, 0.f, 0.f, 0.f};
        if (g < 64) {
            float accd[4] = {0.f, 0.f, 0.f, 0.f};
            const int k0 = wv << 8;   // U/4 = 256 per wave
            #pragma unroll 4
            for (int k = k0; k < k0 + 256; ++k) {
                const float xv = hT2[(size_t)k * B + lane];
                const float4 w4 = *(const float4*)(Wd + (size_t)k * F + f0);
                accd[0] = fmaf(w4.x, xv, accd[0]);
                accd[1] = fmaf(w4.y, xv, accd[1]);
                accd[2] = fmaf(w4.z, xv, accd[2]);
                accd[3] = fmaf(w4.w, xv, accd[3]);
            }
            __syncthreads();
            #pragma unroll
            for (int jj = 0; jj < 4; ++jj)
                zbuf[(size_t)(wv * 16 + jj) * WPAD + lane] = accd[jj];
            __syncthreads();
            if (wv == 0) {
                const float4 bd4 = *(const float4*)(bd + f0);
                float s = 0.f, ss = 0.f;
                #pragma unroll
                for (int jj = 0; jj < 4; ++jj) {
                    float y = 0.f;
                    #pragma unroll
                    for (int w = 0; w < 4; ++w)
                        y += zbuf[(size_t)(w * 16 + jj) * WPAD + lane];
                    y += (jj == 0) ? bd4.x : (jj == 1) ? bd4.y : (jj == 2) ? bd4.z : bd4.w;
                    yv[jj] = y;
                    s += y;
                    ss += y * y;
                }
                float* st = stats + (size_t)(t & 1) * 2 * B;
                atomicAdd(&st[lane], s);
                atomicAdd(&st[B + lane], ss);
            }
            __syncthreads();
        }
        grid_barrier(bar, ++epoch);

        // ---------------- LN + ReLU emit ----------------
        if (g < 64 && wv == 0) {
            const float* st = stats + (size_t)(t & 1) * 2 * B;
            const float mu = st[lane] * (1.0f / F);
            const float var = st[B + lane] * (1.0f / F) - mu * mu;
            const float rs = rsqrtf(var + 1e-12f);
            const float4 gm = *(const float4*)(gamma + f0);
            const float4 bt = *(const float4*)(beta + f0);
            float em[4];
            em[0] = fmaxf((yv[0] - mu) * rs * gm.x + bt.x, 0.0f);
            em[1] = fmaxf((yv[1] - mu) * rs * gm.y + bt.y, 0.0f);
            em[2] = fmaxf((yv[2] - mu) * rs * gm.z + bt.z, 0.0f);
            em[3] = fmaxf((yv[3] - mu) * rs * gm.w + bt.w, 0.0f);
            *(float4*)(out + (size_t)lane * (T * F) + (size_t)t * F + f0) =
                make_float4(em[0], em[1], em[2], em[3]);
            if (t + 1 < T) {
                float xn[4];
                if (cond[t + 1] != 0) {
                    const float4 iv = *(const float4*)(input + (size_t)lane * (T * F) +
                                                       (size_t)(t + 1) * F + f0);
                    xn[0] = iv.x; xn[1] = iv.y; xn[2] = iv.z; xn[3] = iv.w;
                } else {
                    xn[0] = em[0]; xn[1] = em[1]; xn[2] = em[2]; xn[3] = em[3];
                }
                #pragma unroll
                for (int jj = 0; jj < 4; ++jj)
                    xb[(size_t)lane * F + f0 + jj] = f2h(xn[jj]);
            }
        }
        if (g == 0 && wv == 1) {   // zero other-parity stats for step t+1
            float* st2 = stats + (size_t)((t + 1) & 1) * 2 * B;
            st2[lane] = 0.0f;
            st2[B + lane] = 0.0f;
        }
        grid_barrier(bar, ++epoch);
    }
}

extern "C" void kernel_launch(void* const* d_in, const int* in_sizes, int n_in,
                              void* d_out, int out_size, void* d_ws, size_t ws_size,
                              hipStream_t stream) {
    const float* input = (const float*)d_in[0];
    const unsigned char* condraw = (const unsigned char*)d_in[1];
    const float* W0 = (const float*)d_in[2];
    const float* b0 = (const float*)d_in[3];
    const float* W1 = (const float*)d_in[4];
    const float* b1 = (const float*)d_in[5];
    const float* W2 = (const float*)d_in[6];
    const float* b2 = (const float*)d_in[7];
    const float* Wd = (const float*)d_in[8];
    const float* bd = (const float*)d_in[9];
    const float* gamma = (const float*)d_in[10];
    const float* beta = (const float*)d_in[11];
    float* out = (float*)d_out;
    unsigned char* wsb = (unsigned char*)d_ws;

    hipMemsetAsync(d_ws, 0, ZERO_BYTES, stream);
    prep_kernel<<<1, 512, 0, stream>>>(condraw, input, wsb);
    repack_kernel<<<2048, 256, 0, stream>>>(W0, W1, W2, wsb);
    lstm_persistent<<<NBLK, NTH, 0, stream>>>(input, b0, b1, b2, Wd, bd,
                                              gamma, beta, out, wsb);
}

// Round 5
// 43306.049 us; speedup vs baseline: 9.7473x; 2.5476x over previous
//
#include <hip/hip_runtime.h>
#include <math.h>

// Problem constants
#define B 64
#define T 512
#define F 256
#define U 1024
#define NBLK 256
#define NTH 512
#define WPAD 68   // zbuf row stride (floats): 68%32=4 -> conflict-free b128 partial stores

typedef unsigned short ushort_t;
typedef __attribute__((ext_vector_type(8))) _Float16 f16x8_t;  // MFMA A/B frag (4 VGPR)
typedef __attribute__((ext_vector_type(4))) float f32x4_t;     // MFMA C/D frag

// ---------------- workspace layout (BYTE offsets) ----------------
static const size_t OFF_HT2  = 0;                  // fp32 h2 [U][B] for dense: 262144
static const size_t OFF_STATS= 262144;             // fp32 [2 parity][2][B]: 1024
static const size_t OFF_COND = 263424;             // int[512]: 2048
static const size_t OFF_BAR  = 265472;             // int[1024]: 4096
static const size_t OFF_HB   = 269568;             // f16 h [2 parity][3 layer][B][U]: 786432
static const size_t OFF_XB   = 1056000;            // f16 xbuf [B][F]: 32768
static const size_t OFF_PW0  = 1088768;            // f16 [256 g][40 kt][64 lane][8]: 10485760
static const size_t OFF_PW1  = 11574528;           // f16 [256][64][64][8]: 16777216
static const size_t OFF_PW2  = 28351744;           // f16 [256][64][64][8]: 16777216
static const size_t WS_BYTES = 45128960;
static const size_t ZERO_BYTES = OFF_PW0;          // state region to zero each launch

__device__ __forceinline__ float sigm(float x) {
    return 1.0f / (1.0f + __expf(-x));
}

__device__ __forceinline__ ushort_t f2h(float x) {   // RNE fp32->fp16
    _Float16 h = (_Float16)x;
    union { _Float16 h; ushort_t u; } v; v.h = h;
    return v.u;
}

// Hierarchical device-scope grid barrier — NON-INVALIDATING polls.
// Round-4 lesson: ACQUIRE polls emit buffer_inv (invalidates the shared
// per-XCD L2) every iteration -> L2 invalidation storm while sibling CUs
// still stream weights. Here: release fence once (wbL2, no inv), RELAXED
// atomic polls (bypass L2 at coherence point, no inv), one acquire fence
// at exit (single inv per barrier). Safety acquire-load every 64 spins.
__device__ __forceinline__ void grid_barrier(int* bar, int epoch) {
    __syncthreads();
    if (threadIdx.x == 0) {
        __builtin_amdgcn_fence(__ATOMIC_RELEASE, "agent");   // wbL2, no inv
        int* sub = bar + (blockIdx.x & 7) * 64;
        int* master = bar + 512;
        int* gen = bar + 576;
        int prev = __hip_atomic_fetch_add(sub, 1, __ATOMIC_RELAXED,
                                          __HIP_MEMORY_SCOPE_AGENT);
        if (prev == 31) {
            int pm = __hip_atomic_fetch_add(master, 1, __ATOMIC_RELAXED,
                                            __HIP_MEMORY_SCOPE_AGENT);
            if (pm == 7) {
                *master = 0;
                #pragma unroll
                for (int i = 0; i < 8; ++i) bar[i * 64] = 0;
                // release store: wbL2 flushes the resets above, then sc1 store
                __hip_atomic_store(gen, epoch, __ATOMIC_RELEASE,
                                   __HIP_MEMORY_SCOPE_AGENT);
            }
        }
        int spins = 0;
        while (__hip_atomic_load(gen, __ATOMIC_RELAXED,
                                 __HIP_MEMORY_SCOPE_AGENT) < epoch) {
            __builtin_amdgcn_s_sleep(2);
            if ((++spins & 63) == 0) {  // hang insurance if relaxed ever caches
                (void)__hip_atomic_load(gen, __ATOMIC_ACQUIRE,
                                        __HIP_MEMORY_SCOPE_AGENT);
            }
        }
        __builtin_amdgcn_fence(__ATOMIC_ACQUIRE, "agent");   // the one inv
    }
    __syncthreads();
}

// Prep: decode conditioned_lst (bool-u8 vs int32 sniff), init f16 xbuf from input[:,0,:].
__global__ void prep_kernel(const unsigned char* __restrict__ condraw,
                            const float* __restrict__ input,
                            unsigned char* __restrict__ wsb) {
    __shared__ int s_not_int32;
    const int tid = threadIdx.x;
    if (tid == 0) s_not_int32 = 0;
    __syncthreads();
    if (tid < 512 && (tid & 3) != 0) {
        if (condraw[tid] != 0) s_not_int32 = 1;
    }
    __syncthreads();
    const int is32 = (s_not_int32 == 0);
    int* condw = (int*)(wsb + OFF_COND);
    if (tid < 512) {
        int cv = is32 ? ((const int*)condraw)[tid] : (int)condraw[tid];
        condw[tid] = (cv != 0) ? 1 : 0;
    }
    ushort_t* xb = (ushort_t*)(wsb + OFF_XB);
    for (int i = tid; i < B * F; i += blockDim.x) {
        const int b = i >> 8, f = i & 255;
        xb[i] = f2h(input[(size_t)b * (T * F) + f]);
    }
}

// Repack fp32 weights -> fp16 in MFMA B-fragment order:
// PW_l[((g*KT + kt)*64 + L)*8 + j] = W_l[k][col], k = kt*32 + (L>>4)*8 + j,
// n = L&15, col = (n>>2)*1024 + g*4 + (n&3)
__global__ void repack_kernel(const float* __restrict__ W0,
                              const float* __restrict__ W1,
                              const float* __restrict__ W2,
                              unsigned char* __restrict__ wsb) {
    ushort_t* P0 = (ushort_t*)(wsb + OFF_PW0);
    ushort_t* P1 = (ushort_t*)(wsb + OFF_PW1);
    ushort_t* P2 = (ushort_t*)(wsb + OFF_PW2);
    const size_t stride = (size_t)gridDim.x * blockDim.x;
    const size_t tid = (size_t)blockIdx.x * blockDim.x + threadIdx.x;
    const size_t N0 = (size_t)256 * 40 * 512;
    const size_t N12 = (size_t)256 * 64 * 512;
    for (size_t i = tid; i < N0; i += stride) {
        const int g = (int)(i / 20480);
        const int r = (int)(i % 20480);
        const int kt = r >> 9, s = r & 511, L = s >> 3, j = s & 7;
        const int k = kt * 32 + ((L >> 4) << 3) + j;
        const int n = L & 15;
        const int col = ((n >> 2) << 10) + (g << 2) + (n & 3);
        P0[i] = f2h(W0[(size_t)k * 4096 + col]);
    }
    for (size_t i = tid; i < N12; i += stride) {
        const int g = (int)(i / 32768);
        const int r = (int)(i % 32768);
        const int kt = r >> 9, s = r & 511, L = s >> 3, j = s & 7;
        const int k = kt * 32 + ((L >> 4) << 3) + j;
        const int n = L & 15;
        const int col = ((n >> 2) << 10) + (g << 2) + (n & 3);
        const size_t src = (size_t)k * 4096 + col;
        P1[i] = f2h(W1[src]);
        P2[i] = f2h(W2[src]);
    }
}

// One layer's MFMA work for one wave: KTW ktiles, processed in chunks of 4
// with all 20 chunk loads (4 B-frags + 16 A-frags) issued before any MFMA.
template<int KTW>
__device__ __forceinline__ void layer_mfma(const ushort_t* __restrict__ pwb,
                                           int kt0,
                                           const ushort_t* __restrict__ xsrc,
                                           const ushort_t* __restrict__ hsrc,
                                           int K1, int S1,
                                           int lane, int ln15, int kofs,
                                           f32x4_t acc[4]) {
    #pragma unroll
    for (int base = 0; base < KTW; base += 4) {
        const int CH = (KTW - base) < 4 ? (KTW - base) : 4;  // unroll-constant
        f16x8_t Bb[4];
        f16x8_t Ab[4][4];
        #pragma unroll
        for (int c = 0; c < 4; ++c) {
            if (c < CH) {
                const int kt = kt0 + base + c;
                Bb[c] = *(const f16x8_t*)(pwb + (size_t)kt * 512 + lane * 8);
                const int kg = kt * 32;
                const ushort_t* ab;
                int rs;
                if (kg < K1) { ab = xsrc + kg; rs = S1; }
                else         { ab = hsrc + (kg - K1); rs = U; }
                const ushort_t* lp = ab + (size_t)ln15 * rs + kofs;
                #pragma unroll
                for (int mt = 0; mt < 4; ++mt)
                    Ab[c][mt] = *(const f16x8_t*)(lp + (size_t)mt * 16 * rs);
            }
        }
        #pragma unroll
        for (int c = 0; c < 4; ++c) {
            if (c < CH) {
                #pragma unroll
                for (int mt = 0; mt < 4; ++mt)
                    acc[mt] = __builtin_amdgcn_mfma_f32_16x16x32_f16(
                        Ab[c][mt], Bb[c], acc[mt], 0, 0, 0);
            }
        }
    }
}

__global__ void __launch_bounds__(NTH, 2)
lstm_persistent(const float* __restrict__ input,
                const float* __restrict__ b0, const float* __restrict__ b1,
                const float* __restrict__ b2,
                const float* __restrict__ Wd, const float* __restrict__ bd,
                const float* __restrict__ gamma, const float* __restrict__ beta,
                float* __restrict__ out, unsigned char* __restrict__ wsb) {
    const int g = blockIdx.x;
    const int tid = threadIdx.x;
    const int lane = tid & 63;
    const int wv = __builtin_amdgcn_readfirstlane(tid >> 6);  // 0..7
    const int ln15 = lane & 15;
    const int quad = lane >> 4;
    const int kofs = quad << 3;

    float* hT2 = (float*)(wsb + OFF_HT2);          // fp32 [U][B]
    float* stats = (float*)(wsb + OFF_STATS);
    const int* cond = (const int*)(wsb + OFF_COND);
    int* bar = (int*)(wsb + OFF_BAR);
    ushort_t* hb = (ushort_t*)(wsb + OFF_HB);      // f16 [2][3][B][U]
    ushort_t* xb = (ushort_t*)(wsb + OFF_XB);      // f16 [B][F]
    const ushort_t* PWa[3] = {(const ushort_t*)(wsb + OFF_PW0),
                              (const ushort_t*)(wsb + OFF_PW1),
                              (const ushort_t*)(wsb + OFF_PW2)};

    __shared__ float zbuf[128 * WPAD];   // [wv*16+n][m]; 34.8 KB

    const int u0 = g << 2;   // block's unit quad
    const int f0 = g << 2;   // dense cols (g < 64)

    // epilogue mapping (first 4 waves): thread -> (batch eb, unit-in-quad eu)
    const int eb = tid & 63;
    const int eu = (tid >> 6) & 3;
    float creg[3] = {0.f, 0.f, 0.f};   // fp32 cell state (valid for tid<256)

    int epoch = 0;
    for (int t = 0; t < T; ++t) {
        const int p = t & 1;
        const int pn = p ^ 1;

        // ---------------- LSTM layers: MFMA z^(l) = X W ----------------
        for (int l = 0; l < 3; ++l) {
            const int K1 = (l == 0) ? F : U;
            const int S1 = (l == 0) ? F : U;
            const ushort_t* xsrc = (l == 0) ? xb
                                 : (hb + ((size_t)(pn * 3 + (l - 1))) * B * U);
            const ushort_t* hsrc = hb + ((size_t)(p * 3 + l)) * B * U;
            const ushort_t* pwb = PWa[l] + (size_t)g * ((l == 0) ? 40 : 64) * 512;

            f32x4_t acc[4];
            #pragma unroll
            for (int mt = 0; mt < 4; ++mt) acc[mt] = (f32x4_t){0.f, 0.f, 0.f, 0.f};

            if (l == 0) layer_mfma<5>(pwb, wv * 5, xsrc, hsrc, K1, S1,
                                      lane, ln15, kofs, acc);
            else        layer_mfma<8>(pwb, wv * 8, xsrc, hsrc, K1, S1,
                                      lane, ln15, kofs, acc);

            // cross-wave K reduction via LDS: row = wv*16 + n
            __syncthreads();
            {
                float* zrow = zbuf + (size_t)(wv * 16 + ln15) * WPAD;
                #pragma unroll
                for (int mt = 0; mt < 4; ++mt)
                    *(f32x4_t*)(zrow + mt * 16 + (quad << 2)) = acc[mt];
            }
            __syncthreads();

            // gate epilogue on first 4 waves: (b=eb, unit u0+eu)
            if (tid < 256) {
                const float* bvec = (l == 0) ? b0 : ((l == 1) ? b1 : b2);
                float z[4];
                #pragma unroll
                for (int q = 0; q < 4; ++q) {
                    float s = bvec[(q << 10) + u0 + eu];
                    #pragma unroll
                    for (int w = 0; w < 8; ++w)
                        s += zbuf[(size_t)(w * 16 + q * 4 + eu) * WPAD + eb];
                    z[q] = s;
                }
                const float ig = sigm(z[0]);
                const float gg = tanhf(z[1]);
                const float fg = sigm(z[2] + 1.0f);   // forget_bias = 1.0
                const float og = sigm(z[3]);
                const float cn = creg[l] * fg + ig * gg;
                const float hn = og * tanhf(cn);
                creg[l] = cn;
                hb[((size_t)(pn * 3 + l)) * B * U + (size_t)eb * U + u0 + eu] = f2h(hn);
                if (l == 2) hT2[(size_t)(u0 + eu) * B + eb] = hn;
            }
            grid_barrier(bar, ++epoch);
        }

        // ---------------- dense projection + LN stats (fp32 VALU) ----------------
        float yv[4] = {0.f, 0.f, 0.f, 0.f};
        if (g < 64) {
            float accd[4] = {0.f, 0.f, 0.f, 0.f};
            const int k0 = wv << 7;   // U/8 = 128 per wave
            #pragma unroll 4
            for (int k = k0; k < k0 + 128; ++k) {
                const float xv = hT2[(size_t)k * B + lane];
                const float4 w4 = *(const float4*)(Wd + (size_t)k * F + f0);
                accd[0] = fmaf(w4.x, xv, accd[0]);
                accd[1] = fmaf(w4.y, xv, accd[1]);
                accd[2] = fmaf(w4.z, xv, accd[2]);
                accd[3] = fmaf(w4.w, xv, accd[3]);
            }
            __syncthreads();
            #pragma unroll
            for (int jj = 0; jj < 4; ++jj)
                zbuf[(size_t)(wv * 16 + jj) * WPAD + lane] = accd[jj];
            __syncthreads();
            if (wv == 0) {
                const float4 bd4 = *(const float4*)(bd + f0);
                float s = 0.f, ss = 0.f;
                #pragma unroll
                for (int jj = 0; jj < 4; ++jj) {
                    float y = 0.f;
                    #pragma unroll
                    for (int w = 0; w < 8; ++w)
                        y += zbuf[(size_t)(w * 16 + jj) * WPAD + lane];
                    y += (jj == 0) ? bd4.x : (jj == 1) ? bd4.y : (jj == 2) ? bd4.z : bd4.w;
                    yv[jj] = y;
                    s += y;
                    ss += y * y;
                }
                float* st = stats + (size_t)(t & 1) * 2 * B;
                atomicAdd(&st[lane], s);
                atomicAdd(&st[B + lane], ss);
            }
            __syncthreads();
        }
        grid_barrier(bar, ++epoch);

        // ---------------- LN + ReLU emit ----------------
        if (g < 64 && wv == 0) {
            const float* st = stats + (size_t)(t & 1) * 2 * B;
            const float mu = st[lane] * (1.0f / F);
            const float var = st[B + lane] * (1.0f / F) - mu * mu;
            const float rs = rsqrtf(var + 1e-12f);
            const float4 gm = *(const float4*)(gamma + f0);
            const float4 bt = *(const float4*)(beta + f0);
            float em[4];
            em[0] = fmaxf((yv[0] - mu) * rs * gm.x + bt.x, 0.0f);
            em[1] = fmaxf((yv[1] - mu) * rs * gm.y + bt.y, 0.0f);
            em[2] = fmaxf((yv[2] - mu) * rs * gm.z + bt.z, 0.0f);
            em[3] = fmaxf((yv[3] - mu) * rs * gm.w + bt.w, 0.0f);
            *(float4*)(out + (size_t)lane * (T * F) + (size_t)t * F + f0) =
                make_float4(em[0], em[1], em[2], em[3]);
            if (t + 1 < T) {
                float xn[4];
                if (cond[t + 1] != 0) {
                    const float4 iv = *(const float4*)(input + (size_t)lane * (T * F) +
                                                       (size_t)(t + 1) * F + f0);
                    xn[0] = iv.x; xn[1] = iv.y; xn[2] = iv.z; xn[3] = iv.w;
                } else {
                    xn[0] = em[0]; xn[1] = em[1]; xn[2] = em[2]; xn[3] = em[3];
                }
                #pragma unroll
                for (int jj = 0; jj < 4; ++jj)
                    xb[(size_t)lane * F + f0 + jj] = f2h(xn[jj]);
            }
        }
        if (g == 0 && wv == 1) {   // zero other-parity stats for step t+1
            float* st2 = stats + (size_t)((t + 1) & 1) * 2 * B;
            st2[lane] = 0.0f;
            st2[B + lane] = 0.0f;
        }
        grid_barrier(bar, ++epoch);
    }
}

extern "C" void kernel_launch(void* const* d_in, const int* in_sizes, int n_in,
                              void* d_out, int out_size, void* d_ws, size_t ws_size,
                              hipStream_t stream) {
    const float* input = (const float*)d_in[0];
    const unsigned char* condraw = (const unsigned char*)d_in[1];
    const float* W0 = (const float*)d_in[2];
    const float* b0 = (const float*)d_in[3];
    const float* W1 = (const float*)d_in[4];
    const float* b1 = (const float*)d_in[5];
    const float* W2 = (const float*)d_in[6];
    const float* b2 = (const float*)d_in[7];
    const float* Wd = (const float*)d_in[8];
    const float* bd = (const float*)d_in[9];
    const float* gamma = (const float*)d_in[10];
    const float* beta = (const float*)d_in[11];
    float* out = (float*)d_out;
    unsigned char* wsb = (unsigned char*)d_ws;

    hipMemsetAsync(d_ws, 0, ZERO_BYTES, stream);
    prep_kernel<<<1, 512, 0, stream>>>(condraw, input, wsb);
    repack_kernel<<<2048, 256, 0, stream>>>(W0, W1, W2, wsb);
    lstm_persistent<<<NBLK, NTH, 0, stream>>>(input, b0, b1, b2, Wd, bd,
                                              gamma, beta, out, wsb);
}